// Round 5
// baseline (581.971 us; speedup 1.0000x reference)
//
#include <hip/hip_runtime.h>
#include <hip/hip_bf16.h>
#include <math.h>

// Problem constants
#define S_LEN 2048
#define DIM   2048
#define H_N   16
#define NOPE  128
#define ROPE  64
#define VD    128
#define LORA  512
#define D_QK  576
#define SCALE_F 0.07216878364870323f   // 192^-0.5
#define EPS_F 1e-6f
#define KVF 640                        // padded kv row (f32 elems)
#define KVS 1280                       // padded kv row (shorts)

typedef short short8 __attribute__((ext_vector_type(8)));
typedef short short4v __attribute__((ext_vector_type(4)));
typedef float floatx4 __attribute__((ext_vector_type(4)));

static __device__ inline unsigned short f2bf_bits(float f) {
  union { __hip_bfloat16 h; unsigned short u; } cv;
  cv.h = __float2bfloat16(f);
  return cv.u;
}

static __device__ inline float bf2f(unsigned short b) {
  union { unsigned u; float f; } cv;
  cv.u = (unsigned)b << 16;
  return cv.f;
}

// global_load_lds: LDS destination must be WAVE-UNIFORM; lane's 16B lands at
// base + lane*16 automatically.
static __device__ inline void gload_lds16(const short* gptr, short* lds_base_uniform) {
  __builtin_amdgcn_global_load_lds(
      (const __attribute__((address_space(1))) void*)gptr,
      (__attribute__((address_space(3))) void*)lds_base_uniform, 16, 0, 0);
}

// ---------------------------------------------------------------------------
// elementwise f32 -> bf16 cast, 8 elts/thread
// ---------------------------------------------------------------------------
__global__ __launch_bounds__(256) void cast_f32_bf16(
    const float* __restrict__ src, short* __restrict__ dst, int n8) {
  int i = blockIdx.x * 256 + threadIdx.x;
  if (i < n8) {
    float4 a = ((const float4*)src)[2 * i];
    float4 b = ((const float4*)src)[2 * i + 1];
    uint4 o;
    o.x = (unsigned)f2bf_bits(a.x) | ((unsigned)f2bf_bits(a.y) << 16);
    o.y = (unsigned)f2bf_bits(a.z) | ((unsigned)f2bf_bits(a.w) << 16);
    o.z = (unsigned)f2bf_bits(b.x) | ((unsigned)f2bf_bits(b.y) << 16);
    o.w = (unsigned)f2bf_bits(b.z) | ((unsigned)f2bf_bits(b.w) << 16);
    ((uint4*)dst)[i] = o;
  }
}

// zero n8 uint4-chunks (8 shorts each)
__global__ __launch_bounds__(256) void zero_short8(short* __restrict__ dst, int n8) {
  int i = blockIdx.x * 256 + threadIdx.x;
  if (i < n8) ((uint4*)dst)[i] = (uint4){0u, 0u, 0u, 0u};
}

// ---------------------------------------------------------------------------
// wukT[h][c][d] = wkv_b[h*256 + d][c]  (f32 in, bf16 out), c<512, d<128
// ---------------------------------------------------------------------------
__global__ __launch_bounds__(256) void transpose_wuk(
    const float* __restrict__ wkvb, short* __restrict__ wukT) {
  __shared__ float tile[32][33];
  const int h = blockIdx.z, c0 = blockIdx.y * 32, d0 = blockIdx.x * 32;
  const int t = threadIdx.x;
  const int r = t >> 3, c4 = (t & 7) * 4;
  float4 v = *(const float4*)(wkvb + ((long)h * 256 + d0 + r) * 512 + c0 + c4);
  tile[r][c4 + 0] = v.x; tile[r][c4 + 1] = v.y;
  tile[r][c4 + 2] = v.z; tile[r][c4 + 3] = v.w;
  __syncthreads();
  uint2 o;
  o.x = (unsigned)f2bf_bits(tile[c4 + 0][r]) | ((unsigned)f2bf_bits(tile[c4 + 1][r]) << 16);
  o.y = (unsigned)f2bf_bits(tile[c4 + 2][r]) | ((unsigned)f2bf_bits(tile[c4 + 3][r]) << 16);
  *(uint2*)(wukT + ((long)h * 512 + c0 + r) * 128 + d0 + c4) = o;
}

// ---------------------------------------------------------------------------
// bf16 MFMA NT GEMM: C[m,n] = sum_k A[m,k]*B[n,k]. Output f32 or bf16.
// Double-buffered LDS (2x16KB) with 1-deep prefetch.
// ---------------------------------------------------------------------------
__global__ __launch_bounds__(256) void gemm_bf16_nt(
    const short* __restrict__ A, const short* __restrict__ B, void* __restrict__ Cv,
    int K, int lda, int ldb, int ldc, long aB, long bB, long cB, int bf16out) {
  A += (long)blockIdx.z * aB;
  B += (long)blockIdx.z * bB;
  const int m0 = blockIdx.y * 128, n0 = blockIdx.x * 128;
  __shared__ short As[2][128 * 32];
  __shared__ short Bs[2][128 * 32];
  const int tid = threadIdx.x, w = tid >> 6, lane = tid & 63;
  const int ln = lane & 15, g = lane >> 4;
  const int mw = (w & 1) * 64, nw = (w >> 1) * 64;
  floatx4 acc[4][4];
#pragma unroll
  for (int i = 0; i < 4; ++i)
#pragma unroll
    for (int j = 0; j < 4; ++j) acc[i][j] = (floatx4){0.f, 0.f, 0.f, 0.f};

#define GEMM_STAGE(k0_, b_)                                                    \
  {                                                                            \
    _Pragma("unroll")                                                          \
    for (int i = 0; i < 2; ++i) {                                              \
      const int bc = (i * 4 + w) * 64;                                         \
      const int c = bc + lane;                                                 \
      const int row = c >> 2, quar = c & 3;                                    \
      gload_lds16(A + (long)(m0 + row) * lda + (k0_) + quar * 8, As[b_] + bc * 8); \
      gload_lds16(B + (long)(n0 + row) * ldb + (k0_) + quar * 8, Bs[b_] + bc * 8); \
    }                                                                          \
  }

  GEMM_STAGE(0, 0);
  __syncthreads();
  const int nk = K >> 5;
  for (int kt = 0; kt < nk; ++kt) {
    const int cb = kt & 1;
    if (kt + 1 < nk) GEMM_STAGE((kt + 1) << 5, cb ^ 1);
    short8 af[4], bf_[4];
#pragma unroll
    for (int mi = 0; mi < 4; ++mi)
      af[mi] = *(const short8*)(As[cb] + (mw + mi * 16 + ln) * 32 + g * 8);
#pragma unroll
    for (int ni = 0; ni < 4; ++ni)
      bf_[ni] = *(const short8*)(Bs[cb] + (nw + ni * 16 + ln) * 32 + g * 8);
#pragma unroll
    for (int mi = 0; mi < 4; ++mi)
#pragma unroll
      for (int ni = 0; ni < 4; ++ni)
        acc[mi][ni] = __builtin_amdgcn_mfma_f32_16x16x32_bf16(af[mi], bf_[ni], acc[mi][ni], 0, 0, 0);
    __syncthreads();
  }
#undef GEMM_STAGE
  if (bf16out) {
    short* Cs = (short*)Cv + (long)blockIdx.z * cB;
#pragma unroll
    for (int mi = 0; mi < 4; ++mi)
#pragma unroll
      for (int ni = 0; ni < 4; ++ni)
#pragma unroll
        for (int r = 0; r < 4; ++r)
          Cs[(long)(m0 + mw + mi * 16 + g * 4 + r) * ldc + n0 + nw + ni * 16 + ln] =
              (short)f2bf_bits(acc[mi][ni][r]);
  } else {
    float* C = (float*)Cv + (long)blockIdx.z * cB;
#pragma unroll
    for (int mi = 0; mi < 4; ++mi)
#pragma unroll
      for (int ni = 0; ni < 4; ++ni)
#pragma unroll
        for (int r = 0; r < 4; ++r)
          C[(long)(m0 + mw + mi * 16 + g * 4 + r) * ldc + n0 + nw + ni * 16 + ln] = acc[mi][ni][r];
  }
}

// ---------------------------------------------------------------------------
// prep: RMSNorm + RoPE on kv rows (f32 stride KVF) -> bf16 in place (short
// stride KVS, first 576 valid); q_pe RoPE from bf16 qbufb -> bf16 qhat tail
// ---------------------------------------------------------------------------
__global__ __launch_bounds__(64) void prep_kernel(
    float* kv, const short* __restrict__ qbufb, short* __restrict__ qhatb,
    const float* __restrict__ cosp, const float* __restrict__ sinp,
    const float* __restrict__ normw) {
  const int s = blockIdx.x;
  const int l = threadIdx.x;
  float* row = kv + (long)s * KVF;
  short* krow = (short*)kv + (long)s * KVS;

  float4 v0 = *(const float4*)(row + l * 8);
  float4 v1 = *(const float4*)(row + l * 8 + 4);
  float rx0 = 0.f, rx1 = 0.f, rc = 0.f, rs = 0.f;
  if (l < 32) {
    rc = cosp[s * 32 + l];
    rs = sinp[s * 32 + l];
    rx0 = row[512 + 2 * l];
    rx1 = row[512 + 2 * l + 1];
  }
  float4 w0 = *(const float4*)(normw + l * 8);
  float4 w1 = *(const float4*)(normw + l * 8 + 4);

  float ss = v0.x * v0.x + v0.y * v0.y + v0.z * v0.z + v0.w * v0.w +
             v1.x * v1.x + v1.y * v1.y + v1.z * v1.z + v1.w * v1.w;
#pragma unroll
  for (int off = 32; off; off >>= 1) ss += __shfl_xor(ss, off, 64);
  const float scale = rsqrtf(ss * (1.0f / (float)LORA) + EPS_F);
  v0.x *= scale * w0.x; v0.y *= scale * w0.y; v0.z *= scale * w0.z; v0.w *= scale * w0.w;
  v1.x *= scale * w1.x; v1.y *= scale * w1.y; v1.z *= scale * w1.z; v1.w *= scale * w1.w;

  uint4 pk;
  pk.x = (unsigned)f2bf_bits(v0.x) | ((unsigned)f2bf_bits(v0.y) << 16);
  pk.y = (unsigned)f2bf_bits(v0.z) | ((unsigned)f2bf_bits(v0.w) << 16);
  pk.z = (unsigned)f2bf_bits(v1.x) | ((unsigned)f2bf_bits(v1.y) << 16);
  pk.w = (unsigned)f2bf_bits(v1.z) | ((unsigned)f2bf_bits(v1.w) << 16);
  *(uint4*)(krow + l * 8) = pk;

  if (l < 32) {
    const float y0 = rx0 * rc - rx1 * rs;
    const float y1 = rx0 * rs + rx1 * rc;
    unsigned pr = (unsigned)f2bf_bits(y0) | ((unsigned)f2bf_bits(y1) << 16);
    *(unsigned*)(krow + 512 + 2 * l) = pr;
  }

#pragma unroll
  for (int it = 0; it < 8; ++it) {
    const int p = it * 64 + l;
    const int h = p >> 5;
    const int i = p & 31;
    const float c = cosp[s * 32 + i];
    const float sn = sinp[s * 32 + i];
    const short* qp = qbufb + (long)s * 3072 + h * 192 + NOPE;
    const unsigned uq = *(const unsigned*)(qp + 2 * i);
    const float x0 = bf2f((unsigned short)uq);
    const float x1 = bf2f((unsigned short)(uq >> 16));
    const float y0 = x0 * c - x1 * sn;
    const float y1 = x0 * sn + x1 * c;
    short* dst = qhatb + ((long)h * S_LEN + s) * D_QK + 512;
    *(unsigned*)(dst + 2 * i) = (unsigned)f2bf_bits(y0) | ((unsigned)f2bf_bits(y1) << 16);
  }
}

// ---------------------------------------------------------------------------
// Transpose V: kvt[d][s] = kbf[s][d], d<512. kbf rows stride KVS shorts.
// ---------------------------------------------------------------------------
__global__ __launch_bounds__(256) void transpose_v(
    const short* __restrict__ kbf, short* __restrict__ kvt) {
  __shared__ short tile[32][36];
  const int d0 = blockIdx.x * 32;
  const int s0 = blockIdx.y * 32;
  const int t = threadIdx.x;
  const int r = t >> 3;
  const int c4 = (t & 7) * 4;
  uint2 v = *(const uint2*)(kbf + (long)(s0 + r) * KVS + d0 + c4);
  *(uint2*)(&tile[r][c4]) = v;
  __syncthreads();
  uint2 o;
  o.x = (unsigned)(unsigned short)tile[c4 + 0][r] | ((unsigned)(unsigned short)tile[c4 + 1][r] << 16);
  o.y = (unsigned)(unsigned short)tile[c4 + 2][r] | ((unsigned)(unsigned short)tile[c4 + 3][r] << 16);
  *(uint2*)(kvt + (long)(d0 + r) * S_LEN + s0 + c4) = o;
}

// ---------------------------------------------------------------------------
// Fragment-major K: ktt[kt][c][lane][8]
// ---------------------------------------------------------------------------
__global__ __launch_bounds__(256) void build_ktt(
    const short* __restrict__ kbf, short* __restrict__ ktt) {
  const int kt = blockIdx.x;                     // 0..127
  for (int idx = threadIdx.x; idx < 18 * 64; idx += 256) {
    const int c = idx >> 6, l = idx & 63;
    const int ln = l & 15, g = l >> 4;
    uint4 v = *(const uint4*)(kbf + (long)(kt * 16 + ln) * KVS + c * 32 + g * 8);
    *(uint4*)(ktt + ((long)(kt * 18 + c) * 64 + l) * 8) = v;
  }
}

// ---------------------------------------------------------------------------
// Fragment-major V^T: vtt[kt][nt][lane][8]
// ---------------------------------------------------------------------------
__global__ __launch_bounds__(256) void build_vtt(
    const short* __restrict__ kvt, short* __restrict__ vtt) {
  const int kt = blockIdx.x;                     // 0..63
  for (int idx = threadIdx.x; idx < 32 * 64; idx += 256) {
    const int nt = idx >> 6, l = idx & 63;
    const int ln = l & 15, g = l >> 4;
    uint4 v = *(const uint4*)(kvt + (long)(nt * 16 + ln) * S_LEN + kt * 32 + g * 8);
    *(uint4*)(vtt + ((long)(kt * 32 + nt) * 64 + l) * 8) = v;
  }
}

// ---------------------------------------------------------------------------
// Flash v10: block = 256 thr = 4 waves = (2 heads x 2 dh) of one q-tile.
// CHANGES vs v9:
//  * NO LDS staging, NO barriers. K fragments are read directly from
//    global (frag-major ktt) like V already was: ktt (2.36 MB) + vtt (2 MB)
//    fit each XCD's 4 MB L2, and one 18 KB K-tile fits the 32 KB L1, so the
//    4 waves sharing a tile hit L1/L2. This deletes the per-tile
//    vmcnt(0)+s_barrier drain (the structural stall: ~1700 cyc/tile vs
//    ~250 cyc of MFMA) and lets waves free-run with 4 independent MFMA
//    chains (sA0/sA1/sB0/sB1) whose loads the compiler can hoist.
//  * Residency: no LDS cap; regs ~170 -> 3 blocks/CU (was 2).
//  * Longest-first map + setprio retained (both verified wins).
// ---------------------------------------------------------------------------
__global__ __launch_bounds__(256, 2) void flash_reg(
    const short* __restrict__ qhat,   // [H][S][576] bf16
    const short* __restrict__ ktt,    // [128][18][64][8] bf16 frag-major K
    const short* __restrict__ vtt,    // [64][32][64][8] bf16 frag-major V^T
    short* __restrict__ obuf) {       // [H][S][512] bf16
  const int bid = blockIdx.x;         // 0..1023
  const int hp = bid & 7;             // head pair
  const int v = bid >> 3;             // 0..127
  const int vi = v & 31, vj = v >> 5;
  const int qw = (vj == 0) ? 127 - vi : (vj == 1) ? 64 + vi : (vj == 2) ? 63 - vi : vi;
  const int q0 = qw * 16;
  const int tid = threadIdx.x;
  const int w = tid >> 6;             // wave 0..3
  const int lane = tid & 63;
  const int ln = lane & 15, g = lane >> 4;
  const int h = hp * 2 + (w & 1);
  const int dh = w >> 1;
  const int vbase = dh * 256;
  const int qlim = q0 + ln;

  // Q B-frags for this wave's head: n = ln (query), k = g*8+j  (bf16 direct)
  short8 qfr[18];
  {
    const short* qrow = qhat + ((long)h * S_LEN + q0 + ln) * D_QK;
#pragma unroll
    for (int c = 0; c < 18; ++c)
      qfr[c] = *(const short8*)(qrow + c * 32 + g * 8);
  }

  floatx4 oacc[16];
#pragma unroll
  for (int nt = 0; nt < 16; ++nt) oacc[nt] = (floatx4){0.f, 0.f, 0.f, 0.f};
  float lsum = 0.f;

  const int npairs = (qw + 2) >> 1;   // 32-key steps

  for (int p = 0; p < npairs; ++p) {
    const int t0 = p * 32;
    const short* kbA = ktt + (long)(2 * p) * (18 * 512);   // keys t0..t0+15
    const short* kbB = kbA + 18 * 512;                     // keys t0+16..t0+31
    // ---- QK^T: 36 MFMAs, 4 independent accumulator chains, K from L1/L2 ----
    floatx4 sA0 = (floatx4){0.f, 0.f, 0.f, 0.f};
    floatx4 sA1 = (floatx4){0.f, 0.f, 0.f, 0.f};
    floatx4 sB0 = (floatx4){0.f, 0.f, 0.f, 0.f};
    floatx4 sB1 = (floatx4){0.f, 0.f, 0.f, 0.f};
    __builtin_amdgcn_s_setprio(1);
#pragma unroll
    for (int c = 0; c < 18; c += 2) {
      short8 a0 = *(const short8*)(kbA + (c * 64 + lane) * 8);
      short8 a1 = *(const short8*)(kbA + ((c + 1) * 64 + lane) * 8);
      short8 b0 = *(const short8*)(kbB + (c * 64 + lane) * 8);
      short8 b1 = *(const short8*)(kbB + ((c + 1) * 64 + lane) * 8);
      sA0 = __builtin_amdgcn_mfma_f32_16x16x32_bf16(a0, qfr[c], sA0, 0, 0, 0);
      sB0 = __builtin_amdgcn_mfma_f32_16x16x32_bf16(b0, qfr[c], sB0, 0, 0, 0);
      sA1 = __builtin_amdgcn_mfma_f32_16x16x32_bf16(a1, qfr[c + 1], sA1, 0, 0, 0);
      sB1 = __builtin_amdgcn_mfma_f32_16x16x32_bf16(b1, qfr[c + 1], sB1, 0, 0, 0);
    }
    __builtin_amdgcn_s_setprio(0);
    // ---- exp + causal mask; A keys t0+4g+r, B keys t0+16+4g+r ----
    short4v pA4, pB4;
    float psum = 0.f;
#pragma unroll
    for (int r = 0; r < 4; ++r) {
      const int kAi = t0 + g * 4 + r;
      const int kBi = kAi + 16;
      float scA = fminf(fmaxf((sA0[r] + sA1[r]) * SCALE_F, -30.f), 30.f);
      float scB = fminf(fmaxf((sB0[r] + sB1[r]) * SCALE_F, -30.f), 30.f);
      float pA = (kAi <= qlim) ? __expf(scA) : 0.f;
      float pB = (kBi <= qlim) ? __expf(scB) : 0.f;
      psum += pA + pB;
      pA4[r] = (short)f2bf_bits(pA);
      pB4[r] = (short)f2bf_bits(pB);
    }
    lsum += psum;
    // ---- build P^T B-frag for K=32 ----
    union { short4v s; int i[2]; } ua, ub;
    ua.s = pA4; ub.s = pB4;
    const int lolane = ln + ((g & 1) << 5);
    const int hilane = lolane + 16;
    int alo0 = __shfl(ua.i[0], lolane, 64), alo1 = __shfl(ua.i[1], lolane, 64);
    int ahi0 = __shfl(ua.i[0], hilane, 64), ahi1 = __shfl(ua.i[1], hilane, 64);
    int blo0 = __shfl(ub.i[0], lolane, 64), blo1 = __shfl(ub.i[1], lolane, 64);
    int bhi0 = __shfl(ub.i[0], hilane, 64), bhi1 = __shfl(ub.i[1], hilane, 64);
    union { short8 s; int i[4]; } up;
    const bool useA = (g < 2);
    up.i[0] = useA ? alo0 : blo0;
    up.i[1] = useA ? alo1 : blo1;
    up.i[2] = useA ? ahi0 : bhi0;
    up.i[3] = useA ? ahi1 : bhi1;
    const short8 pb8 = up.s;
    // ---- PV: frag-major streaming V loads from L2, K=32 ----
    const short* vp = vtt + (((long)p * 32 + dh * 16) * 64 + lane) * 8;
#pragma unroll
    for (int half = 0; half < 2; ++half) {
      short8 va[8];
#pragma unroll
      for (int j = 0; j < 8; ++j)
        va[j] = *(const short8*)(vp + (half * 8 + j) * 512);
      __builtin_amdgcn_s_setprio(1);
#pragma unroll
      for (int j = 0; j < 8; ++j)
        oacc[half * 8 + j] = __builtin_amdgcn_mfma_f32_16x16x32_bf16(va[j], pb8, oacc[half * 8 + j], 0, 0, 0);
      __builtin_amdgcn_s_setprio(0);
    }
  }

  // denominator for query q0+ln: sum over g-groups (within this wave)
  lsum += __shfl_xor(lsum, 16, 64);
  lsum += __shfl_xor(lsum, 32, 64);
  const float inv = 1.0f / fmaxf(lsum, 1e-30f);

  // O^T tile -> bf16 direct: row=g*4+r -> d = vbase+nt*16+g*4+r, col=ln -> q
  short* orow = obuf + ((long)h * S_LEN + q0 + ln) * 512 + vbase + g * 4;
#pragma unroll
  for (int nt = 0; nt < 16; ++nt) {
    unsigned lo = (unsigned)f2bf_bits(oacc[nt][0] * inv) | ((unsigned)f2bf_bits(oacc[nt][1] * inv) << 16);
    unsigned hi = (unsigned)f2bf_bits(oacc[nt][2] * inv) | ((unsigned)f2bf_bits(oacc[nt][3] * inv) << 16);
    unsigned long long st = (unsigned long long)lo | ((unsigned long long)hi << 32);
    *(unsigned long long*)(orow + nt * 16) = st;
  }
}

// ---------------------------------------------------------------------------
// Host launch
// ---------------------------------------------------------------------------
extern "C" void kernel_launch(void* const* d_in, const int* in_sizes, int n_in,
                              void* d_out, int out_size, void* d_ws, size_t ws_size,
                              hipStream_t stream) {
  (void)in_sizes; (void)n_in; (void)out_size; (void)ws_size;
  const float* x      = (const float*)d_in[0];
  const float* cosp   = (const float*)d_in[1];
  const float* sinp   = (const float*)d_in[2];
  const float* wq     = (const float*)d_in[3];
  const float* wkv_a  = (const float*)d_in[4];
  const float* normw  = (const float*)d_in[5];
  const float* wkv_b  = (const float*)d_in[6];
  const float* wo     = (const float*)d_in[7];
  float* out = (float*)d_out;

  float* ws = (float*)d_ws;
  float* qbufR  = ws;                                  // region A: [S,3072] f32-sized (25.2 MB)
  float* kvold  = qbufR + (long)S_LEN * 3072;          // wkv_a-pad bf16 region (4.7 MB)
  float* qhatR  = kvold + (long)S_LEN * D_QK;          // region B: 75.5 MB
  float* obufR  = qhatR + (long)H_N * S_LEN * D_QK;    // region C: 67 MB
  float* oprojR = obufR + (long)H_N * S_LEN * LORA;    // region D: 16.8 MB

  // region D: padded kv [S, KVF] f32 -> bf16 in place
  float* kvpad = oprojR;
  short* kbf = (short*)kvpad;                          // bf16 rows stride KVS
  short* wkvap = (short*)kvold;                        // padded wkv_a bf16 [KVF,2048]

  // region A aliases: qbufb (bf16 q proj, steps 2-6), then K/V transform
  // buffers (step 7+, qbufb dead) packed after it — no overlap in space.
  short* qbufb = (short*)qbufR;                        // [S,3072] bf16 (12.6 MB)
  short* kvt = qbufb + (long)S_LEN * 3072;             // [512][S] bf16, 2 MB
  short* ktt = kvt + (long)512 * S_LEN;                // 2.36 MB frag-major K
  short* vtt = ktt + (long)128 * 18 * 64 * 8;          // 2 MB frag-major V^T

  // region B aliases: qhatb bf16 (written steps 4/6, read step 8), then
  // post-flash bf16 scratch.
  short* qhatb  = (short*)qhatR;                       // [H][S][576] bf16 (37.7 MB)
  short* wkvbb  = qhatb + (long)H_N * S_LEN * D_QK;    // 4096x512
  short* oprojb = wkvbb + (long)4096 * 512;            // [S,2048] bf16
  short* wob    = oprojb + (long)2048 * 2048;          // 2048x2048

  // region C aliases: pre-flash bf16 scratch (dead by step 8), then flash
  // output obufb overlapping them in space only.
  short* xb   = (short*)obufR;                         // 2048x2048 (dead after step 3)
  short* wqb  = xb  + (long)2048 * 2048;               // 3072x2048 (dead after step 2)
  short* wukT = wqb + (long)3072 * 2048;               // 16x512x128 (dead after step 6)
  short* obufb = (short*)obufR;                        // [H][S][512] bf16 (33.5 MB, step 8+)

  // 1) casts for projections
  cast_f32_bf16<<<dim3(2048), 256, 0, stream>>>(x, xb, 2048 * 2048 / 8);
  cast_f32_bf16<<<dim3(3072), 256, 0, stream>>>(wq, wqb, 3072 * 2048 / 8);
  cast_f32_bf16<<<dim3(576), 256, 0, stream>>>(wkv_a, wkvap, 576 * 2048 / 8);
  zero_short8<<<dim3(64), 256, 0, stream>>>(wkvap + 576L * 2048, 64 * 2048 / 8);

  // 2) qbufb = bf16(x @ wq^T)  (bf16 MFMA, direct bf16 out)
  gemm_bf16_nt<<<dim3(3072 / 128, 2048 / 128, 1), 256, 0, stream>>>(
      xb, wqb, qbufb, 2048, 2048, 2048, 3072, 0, 0, 0, 1);

  // 3) kvpad = x @ wkv_a_pad^T  (f32 out; prep needs f32 for RMSNorm)
  gemm_bf16_nt<<<dim3(KVF / 128, 2048 / 128, 1), 256, 0, stream>>>(
      xb, wkvap, kvpad, 2048, 2048, 2048, KVF, 0, 0, 0, 0);

  // 4) RMSNorm + RoPE (kvpad -> kbf bf16 in place; q_pe -> qhatb tail bf16)
  prep_kernel<<<dim3(S_LEN), 64, 0, stream>>>(kvpad, qbufb, qhatb, cosp, sinp, normw);

  // 5) build wukT
  transpose_wuk<<<dim3(4, 16, 16), 256, 0, stream>>>(wkv_b, wukT);

  // 6) qhatb[:, :512] = bf16(q_nope @ w_uk)  (batched bf16 MFMA NT vs wukT)
  gemm_bf16_nt<<<dim3(512 / 128, 2048 / 128, 16), 256, 0, stream>>>(
      qbufb, wukT, qhatb, 128, 3072, 128, 576,
      192L, 512L * 128, (long)S_LEN * D_QK, 1);

  // 7) K/V layout transforms
  transpose_v<<<dim3(16, 64), 256, 0, stream>>>(kbf, kvt);
  build_ktt<<<dim3(128), 256, 0, stream>>>(kbf, ktt);
  build_vtt<<<dim3(64), 256, 0, stream>>>(kvt, vtt);

  // 8) flash attention -> obufb bf16  (barrier-free, K/V direct from L2)
  flash_reg<<<dim3(1024), 256, 0, stream>>>(qhatb, ktt, vtt, obufb);

  // 9) cast w_uv source
  cast_f32_bf16<<<dim3(1024), 256, 0, stream>>>(wkv_b, wkvbb, 4096 * 512 / 8);

  // 10) oprojb[s, h*128+d] = bf16(sum_c obufb[h,s,c] * w_uv[h,d,c])
  gemm_bf16_nt<<<dim3(1, 2048 / 128, 16), 256, 0, stream>>>(
      obufb, wkvbb + 128L * 512, oprojb, 512, 512, 512, 2048,
      (long)S_LEN * 512, 256L * 512, 128L, 1);

  // 11) out = oprojb @ wo^T  (f32 out)
  cast_f32_bf16<<<dim3(2048), 256, 0, stream>>>(wo, wob, 2048 * 2048 / 8);
  gemm_bf16_nt<<<dim3(2048 / 128, 2048 / 128, 1), 256, 0, stream>>>(
      oprojb, wob, out, 2048, 2048, 2048, 2048, 0, 0, 0, 0);
}

// Round 6
// 462.191 us; speedup vs baseline: 1.2592x; 1.2592x over previous
//
#include <hip/hip_runtime.h>
#include <hip/hip_bf16.h>
#include <math.h>

// Problem constants
#define S_LEN 2048
#define DIM   2048
#define H_N   16
#define NOPE  128
#define ROPE  64
#define VD    128
#define LORA  512
#define D_QK  576
#define SCALE_F 0.07216878364870323f   // 192^-0.5
#define EPS_F 1e-6f
#define KVF 640                        // padded kv row (f32 elems)
#define KVS 1280                       // padded kv row (shorts)

typedef short short8 __attribute__((ext_vector_type(8)));
typedef short short4v __attribute__((ext_vector_type(4)));
typedef float floatx4 __attribute__((ext_vector_type(4)));

static __device__ inline unsigned short f2bf_bits(float f) {
  union { __hip_bfloat16 h; unsigned short u; } cv;
  cv.h = __float2bfloat16(f);
  return cv.u;
}

static __device__ inline float bf2f(unsigned short b) {
  union { unsigned u; float f; } cv;
  cv.u = (unsigned)b << 16;
  return cv.f;
}

// global_load_lds: LDS destination must be WAVE-UNIFORM; lane's 16B lands at
// base + lane*16 automatically.
static __device__ inline void gload_lds16(const short* gptr, short* lds_base_uniform) {
  __builtin_amdgcn_global_load_lds(
      (const __attribute__((address_space(1))) void*)gptr,
      (__attribute__((address_space(3))) void*)lds_base_uniform, 16, 0, 0);
}

// ---------------------------------------------------------------------------
// elementwise f32 -> bf16 cast, 8 elts/thread
// ---------------------------------------------------------------------------
__global__ __launch_bounds__(256) void cast_f32_bf16(
    const float* __restrict__ src, short* __restrict__ dst, int n8) {
  int i = blockIdx.x * 256 + threadIdx.x;
  if (i < n8) {
    float4 a = ((const float4*)src)[2 * i];
    float4 b = ((const float4*)src)[2 * i + 1];
    uint4 o;
    o.x = (unsigned)f2bf_bits(a.x) | ((unsigned)f2bf_bits(a.y) << 16);
    o.y = (unsigned)f2bf_bits(a.z) | ((unsigned)f2bf_bits(a.w) << 16);
    o.z = (unsigned)f2bf_bits(b.x) | ((unsigned)f2bf_bits(b.y) << 16);
    o.w = (unsigned)f2bf_bits(b.z) | ((unsigned)f2bf_bits(b.w) << 16);
    ((uint4*)dst)[i] = o;
  }
}

// zero n8 uint4-chunks (8 shorts each)
__global__ __launch_bounds__(256) void zero_short8(short* __restrict__ dst, int n8) {
  int i = blockIdx.x * 256 + threadIdx.x;
  if (i < n8) ((uint4*)dst)[i] = (uint4){0u, 0u, 0u, 0u};
}

// ---------------------------------------------------------------------------
// wukT[h][c][d] = wkv_b[h*256 + d][c]  (f32 in, bf16 out), c<512, d<128
// ---------------------------------------------------------------------------
__global__ __launch_bounds__(256) void transpose_wuk(
    const float* __restrict__ wkvb, short* __restrict__ wukT) {
  __shared__ float tile[32][33];
  const int h = blockIdx.z, c0 = blockIdx.y * 32, d0 = blockIdx.x * 32;
  const int t = threadIdx.x;
  const int r = t >> 3, c4 = (t & 7) * 4;
  float4 v = *(const float4*)(wkvb + ((long)h * 256 + d0 + r) * 512 + c0 + c4);
  tile[r][c4 + 0] = v.x; tile[r][c4 + 1] = v.y;
  tile[r][c4 + 2] = v.z; tile[r][c4 + 3] = v.w;
  __syncthreads();
  uint2 o;
  o.x = (unsigned)f2bf_bits(tile[c4 + 0][r]) | ((unsigned)f2bf_bits(tile[c4 + 1][r]) << 16);
  o.y = (unsigned)f2bf_bits(tile[c4 + 2][r]) | ((unsigned)f2bf_bits(tile[c4 + 3][r]) << 16);
  *(uint2*)(wukT + ((long)h * 512 + c0 + r) * 128 + d0 + c4) = o;
}

// ---------------------------------------------------------------------------
// bf16 MFMA NT GEMM: C[m,n] = sum_k A[m,k]*B[n,k]. Output f32 or bf16.
// Double-buffered LDS (2x16KB) with 1-deep prefetch.
// ---------------------------------------------------------------------------
__global__ __launch_bounds__(256) void gemm_bf16_nt(
    const short* __restrict__ A, const short* __restrict__ B, void* __restrict__ Cv,
    int K, int lda, int ldb, int ldc, long aB, long bB, long cB, int bf16out) {
  A += (long)blockIdx.z * aB;
  B += (long)blockIdx.z * bB;
  const int m0 = blockIdx.y * 128, n0 = blockIdx.x * 128;
  __shared__ short As[2][128 * 32];
  __shared__ short Bs[2][128 * 32];
  const int tid = threadIdx.x, w = tid >> 6, lane = tid & 63;
  const int ln = lane & 15, g = lane >> 4;
  const int mw = (w & 1) * 64, nw = (w >> 1) * 64;
  floatx4 acc[4][4];
#pragma unroll
  for (int i = 0; i < 4; ++i)
#pragma unroll
    for (int j = 0; j < 4; ++j) acc[i][j] = (floatx4){0.f, 0.f, 0.f, 0.f};

#define GEMM_STAGE(k0_, b_)                                                    \
  {                                                                            \
    _Pragma("unroll")                                                          \
    for (int i = 0; i < 2; ++i) {                                              \
      const int bc = (i * 4 + w) * 64;                                         \
      const int c = bc + lane;                                                 \
      const int row = c >> 2, quar = c & 3;                                    \
      gload_lds16(A + (long)(m0 + row) * lda + (k0_) + quar * 8, As[b_] + bc * 8); \
      gload_lds16(B + (long)(n0 + row) * ldb + (k0_) + quar * 8, Bs[b_] + bc * 8); \
    }                                                                          \
  }

  GEMM_STAGE(0, 0);
  __syncthreads();
  const int nk = K >> 5;
  for (int kt = 0; kt < nk; ++kt) {
    const int cb = kt & 1;
    if (kt + 1 < nk) GEMM_STAGE((kt + 1) << 5, cb ^ 1);
    short8 af[4], bf_[4];
#pragma unroll
    for (int mi = 0; mi < 4; ++mi)
      af[mi] = *(const short8*)(As[cb] + (mw + mi * 16 + ln) * 32 + g * 8);
#pragma unroll
    for (int ni = 0; ni < 4; ++ni)
      bf_[ni] = *(const short8*)(Bs[cb] + (nw + ni * 16 + ln) * 32 + g * 8);
#pragma unroll
    for (int mi = 0; mi < 4; ++mi)
#pragma unroll
      for (int ni = 0; ni < 4; ++ni)
        acc[mi][ni] = __builtin_amdgcn_mfma_f32_16x16x32_bf16(af[mi], bf_[ni], acc[mi][ni], 0, 0, 0);
    __syncthreads();
  }
#undef GEMM_STAGE
  if (bf16out) {
    short* Cs = (short*)Cv + (long)blockIdx.z * cB;
#pragma unroll
    for (int mi = 0; mi < 4; ++mi)
#pragma unroll
      for (int ni = 0; ni < 4; ++ni)
#pragma unroll
        for (int r = 0; r < 4; ++r)
          Cs[(long)(m0 + mw + mi * 16 + g * 4 + r) * ldc + n0 + nw + ni * 16 + ln] =
              (short)f2bf_bits(acc[mi][ni][r]);
  } else {
    float* C = (float*)Cv + (long)blockIdx.z * cB;
#pragma unroll
    for (int mi = 0; mi < 4; ++mi)
#pragma unroll
      for (int ni = 0; ni < 4; ++ni)
#pragma unroll
        for (int r = 0; r < 4; ++r)
          C[(long)(m0 + mw + mi * 16 + g * 4 + r) * ldc + n0 + nw + ni * 16 + ln] = acc[mi][ni][r];
  }
}

// ---------------------------------------------------------------------------
// prep: RMSNorm + RoPE on kv rows (f32 stride KVF) -> bf16 in place (short
// stride KVS, first 576 valid); q_pe RoPE from bf16 qbufb -> bf16 qhat tail
// ---------------------------------------------------------------------------
__global__ __launch_bounds__(64) void prep_kernel(
    float* kv, const short* __restrict__ qbufb, short* __restrict__ qhatb,
    const float* __restrict__ cosp, const float* __restrict__ sinp,
    const float* __restrict__ normw) {
  const int s = blockIdx.x;
  const int l = threadIdx.x;
  float* row = kv + (long)s * KVF;
  short* krow = (short*)kv + (long)s * KVS;

  float4 v0 = *(const float4*)(row + l * 8);
  float4 v1 = *(const float4*)(row + l * 8 + 4);
  float rx0 = 0.f, rx1 = 0.f, rc = 0.f, rs = 0.f;
  if (l < 32) {
    rc = cosp[s * 32 + l];
    rs = sinp[s * 32 + l];
    rx0 = row[512 + 2 * l];
    rx1 = row[512 + 2 * l + 1];
  }
  float4 w0 = *(const float4*)(normw + l * 8);
  float4 w1 = *(const float4*)(normw + l * 8 + 4);

  float ss = v0.x * v0.x + v0.y * v0.y + v0.z * v0.z + v0.w * v0.w +
             v1.x * v1.x + v1.y * v1.y + v1.z * v1.z + v1.w * v1.w;
#pragma unroll
  for (int off = 32; off; off >>= 1) ss += __shfl_xor(ss, off, 64);
  const float scale = rsqrtf(ss * (1.0f / (float)LORA) + EPS_F);
  v0.x *= scale * w0.x; v0.y *= scale * w0.y; v0.z *= scale * w0.z; v0.w *= scale * w0.w;
  v1.x *= scale * w1.x; v1.y *= scale * w1.y; v1.z *= scale * w1.z; v1.w *= scale * w1.w;

  uint4 pk;
  pk.x = (unsigned)f2bf_bits(v0.x) | ((unsigned)f2bf_bits(v0.y) << 16);
  pk.y = (unsigned)f2bf_bits(v0.z) | ((unsigned)f2bf_bits(v0.w) << 16);
  pk.z = (unsigned)f2bf_bits(v1.x) | ((unsigned)f2bf_bits(v1.y) << 16);
  pk.w = (unsigned)f2bf_bits(v1.z) | ((unsigned)f2bf_bits(v1.w) << 16);
  *(uint4*)(krow + l * 8) = pk;

  if (l < 32) {
    const float y0 = rx0 * rc - rx1 * rs;
    const float y1 = rx0 * rs + rx1 * rc;
    unsigned pr = (unsigned)f2bf_bits(y0) | ((unsigned)f2bf_bits(y1) << 16);
    *(unsigned*)(krow + 512 + 2 * l) = pr;
  }

#pragma unroll
  for (int it = 0; it < 8; ++it) {
    const int p = it * 64 + l;
    const int h = p >> 5;
    const int i = p & 31;
    const float c = cosp[s * 32 + i];
    const float sn = sinp[s * 32 + i];
    const short* qp = qbufb + (long)s * 3072 + h * 192 + NOPE;
    const unsigned uq = *(const unsigned*)(qp + 2 * i);
    const float x0 = bf2f((unsigned short)uq);
    const float x1 = bf2f((unsigned short)(uq >> 16));
    const float y0 = x0 * c - x1 * sn;
    const float y1 = x0 * sn + x1 * c;
    short* dst = qhatb + ((long)h * S_LEN + s) * D_QK + 512;
    *(unsigned*)(dst + 2 * i) = (unsigned)f2bf_bits(y0) | ((unsigned)f2bf_bits(y1) << 16);
  }
}

// ---------------------------------------------------------------------------
// Transpose V: kvt[d][s] = kbf[s][d], d<512. kbf rows stride KVS shorts.
// ---------------------------------------------------------------------------
__global__ __launch_bounds__(256) void transpose_v(
    const short* __restrict__ kbf, short* __restrict__ kvt) {
  __shared__ short tile[32][36];
  const int d0 = blockIdx.x * 32;
  const int s0 = blockIdx.y * 32;
  const int t = threadIdx.x;
  const int r = t >> 3;
  const int c4 = (t & 7) * 4;
  uint2 v = *(const uint2*)(kbf + (long)(s0 + r) * KVS + d0 + c4);
  *(uint2*)(&tile[r][c4]) = v;
  __syncthreads();
  uint2 o;
  o.x = (unsigned)(unsigned short)tile[c4 + 0][r] | ((unsigned)(unsigned short)tile[c4 + 1][r] << 16);
  o.y = (unsigned)(unsigned short)tile[c4 + 2][r] | ((unsigned)(unsigned short)tile[c4 + 3][r] << 16);
  *(uint2*)(kvt + (long)(d0 + r) * S_LEN + s0 + c4) = o;
}

// ---------------------------------------------------------------------------
// Fragment-major K: ktt[kt][c][lane][8]
// ---------------------------------------------------------------------------
__global__ __launch_bounds__(256) void build_ktt(
    const short* __restrict__ kbf, short* __restrict__ ktt) {
  const int kt = blockIdx.x;                     // 0..127
  for (int idx = threadIdx.x; idx < 18 * 64; idx += 256) {
    const int c = idx >> 6, l = idx & 63;
    const int ln = l & 15, g = l >> 4;
    uint4 v = *(const uint4*)(kbf + (long)(kt * 16 + ln) * KVS + c * 32 + g * 8);
    *(uint4*)(ktt + ((long)(kt * 18 + c) * 64 + l) * 8) = v;
  }
}

// ---------------------------------------------------------------------------
// Fragment-major V^T: vtt[kt][nt][lane][8]
// ---------------------------------------------------------------------------
__global__ __launch_bounds__(256) void build_vtt(
    const short* __restrict__ kvt, short* __restrict__ vtt) {
  const int kt = blockIdx.x;                     // 0..63
  for (int idx = threadIdx.x; idx < 32 * 64; idx += 256) {
    const int nt = idx >> 6, l = idx & 63;
    const int ln = l & 15, g = l >> 4;
    uint4 v = *(const uint4*)(kvt + (long)(nt * 16 + ln) * S_LEN + kt * 32 + g * 8);
    *(uint4*)(vtt + ((long)(kt * 32 + nt) * 64 + l) * 8) = v;
  }
}

// ---------------------------------------------------------------------------
// Flash v11: block = 256 thr = 4 waves = (2 heads x 2 dh) of one q-tile.
// Lesson from v10 (regressed 189->296): K must stay LDS-staged -- L2-direct
// reads 4x the VMEM requests (no cross-wave sharing) at ~200+ cyc each, and
// the 52 KB/tile working set thrashes the 32 KB L1.
// CHANGES vs v9 (the 189 us version):
//  * Stage at 32-KEY granularity: 2 x 36 KB double buffer. v9's 16-key
//    stages meant even tiles had only ~18 MFMAs (~100 cyc) to hide the
//    ~400 cyc stage latency before the barrier's vmcnt(0) drain. One stage
//    per pair now hides under the FULL pair compute (36 QK MFMA + softmax +
//    shuffle + 16 PV ~ 600 cyc) -> stall ~ 0. Uniform 9 loads/wave/stage;
//    one barrier per 32 keys (was 2).
//  * LDS 72 KB -> 2 blocks/CU, matching the measured effective residency.
//  * Longest-first map + setprio retained (verified wins, rounds 3-4).
// ---------------------------------------------------------------------------
__global__ __launch_bounds__(256, 2) void flash_reg(
    const short* __restrict__ qhat,   // [H][S][576] bf16
    const short* __restrict__ ktt,    // [128][18][64][8] bf16 frag-major K
    const short* __restrict__ vtt,    // [64][32][64][8] bf16 frag-major V^T
    short* __restrict__ obuf) {       // [H][S][512] bf16
  const int bid = blockIdx.x;         // 0..1023
  const int hp = bid & 7;             // head pair
  const int v = bid >> 3;             // 0..127
  const int vi = v & 31, vj = v >> 5;
  const int qw = (vj == 0) ? 127 - vi : (vj == 1) ? 64 + vi : (vj == 2) ? 63 - vi : vi;
  const int q0 = qw * 16;
  const int tid = threadIdx.x;
  const int w = tid >> 6;             // wave 0..3
  const int lane = tid & 63;
  const int ln = lane & 15, g = lane >> 4;
  const int h = hp * 2 + (w & 1);
  const int dh = w >> 1;
  const int vbase = dh * 256;
  const int qlim = q0 + ln;

  __shared__ short Kt[2][36 * 64 * 8];   // 2 x 36 KB double-buffered 32-key pairs

  // Q B-frags for this wave's head: n = ln (query), k = g*8+j  (bf16 direct)
  short8 qfr[18];
  {
    const short* qrow = qhat + ((long)h * S_LEN + q0 + ln) * D_QK;
#pragma unroll
    for (int c = 0; c < 18; ++c)
      qfr[c] = *(const short8*)(qrow + c * 32 + g * 8);
  }

  floatx4 oacc[16];
#pragma unroll
  for (int nt = 0; nt < 16; ++nt) oacc[nt] = (floatx4){0.f, 0.f, 0.f, 0.f};
  float lsum = 0.f;

  const int npairs = (qw + 2) >> 1;   // 32-key steps

  // stage the 32-key pair `pair_` (two consecutive 16-key kt tiles, 36
  // contiguous groups of 64x16B in ktt) into buffer b: 9 issues per wave,
  // wave-uniform LDS base each issue.
#define FL_STAGE(pair_, b_)                                                    \
  {                                                                            \
    const short* ksrc_ = ktt + (long)(pair_) * (36 * 512);                     \
    _Pragma("unroll")                                                          \
    for (int i = 0; i < 9; ++i) {                                              \
      const int grp = i * 4 + w;                                               \
      gload_lds16(ksrc_ + (long)(grp * 64 + lane) * 8, Kt[b_] + grp * 512);    \
    }                                                                          \
  }

  FL_STAGE(0, 0);
  __syncthreads();

  for (int p = 0; p < npairs; ++p) {
    const int cb = p & 1;
    if (p + 1 < npairs) FL_STAGE(p + 1, cb ^ 1);
    const int t0 = p * 32;
    const short* kbA = Kt[cb];              // keys t0..t0+15   (groups 0-17)
    const short* kbB = Kt[cb] + 18 * 512;   // keys t0+16..t0+31 (groups 18-35)
    // ---- QK^T: 36 MFMAs, 4 independent accumulator chains, K from LDS ----
    floatx4 sA0 = (floatx4){0.f, 0.f, 0.f, 0.f};
    floatx4 sA1 = (floatx4){0.f, 0.f, 0.f, 0.f};
    floatx4 sB0 = (floatx4){0.f, 0.f, 0.f, 0.f};
    floatx4 sB1 = (floatx4){0.f, 0.f, 0.f, 0.f};
    __builtin_amdgcn_s_setprio(1);
#pragma unroll
    for (int c = 0; c < 18; c += 2) {
      short8 a0 = *(const short8*)(kbA + (c * 64 + lane) * 8);
      short8 a1 = *(const short8*)(kbA + ((c + 1) * 64 + lane) * 8);
      short8 b0 = *(const short8*)(kbB + (c * 64 + lane) * 8);
      short8 b1 = *(const short8*)(kbB + ((c + 1) * 64 + lane) * 8);
      sA0 = __builtin_amdgcn_mfma_f32_16x16x32_bf16(a0, qfr[c], sA0, 0, 0, 0);
      sB0 = __builtin_amdgcn_mfma_f32_16x16x32_bf16(b0, qfr[c], sB0, 0, 0, 0);
      sA1 = __builtin_amdgcn_mfma_f32_16x16x32_bf16(a1, qfr[c + 1], sA1, 0, 0, 0);
      sB1 = __builtin_amdgcn_mfma_f32_16x16x32_bf16(b1, qfr[c + 1], sB1, 0, 0, 0);
    }
    __builtin_amdgcn_s_setprio(0);
    // ---- exp + causal mask; A keys t0+4g+r, B keys t0+16+4g+r ----
    short4v pA4, pB4;
    float psum = 0.f;
#pragma unroll
    for (int r = 0; r < 4; ++r) {
      const int kAi = t0 + g * 4 + r;
      const int kBi = kAi + 16;
      float scA = fminf(fmaxf((sA0[r] + sA1[r]) * SCALE_F, -30.f), 30.f);
      float scB = fminf(fmaxf((sB0[r] + sB1[r]) * SCALE_F, -30.f), 30.f);
      float pA = (kAi <= qlim) ? __expf(scA) : 0.f;
      float pB = (kBi <= qlim) ? __expf(scB) : 0.f;
      psum += pA + pB;
      pA4[r] = (short)f2bf_bits(pA);
      pB4[r] = (short)f2bf_bits(pB);
    }
    lsum += psum;
    // ---- build P^T B-frag for K=32 ----
    union { short4v s; int i[2]; } ua, ub;
    ua.s = pA4; ub.s = pB4;
    const int lolane = ln + ((g & 1) << 5);
    const int hilane = lolane + 16;
    int alo0 = __shfl(ua.i[0], lolane, 64), alo1 = __shfl(ua.i[1], lolane, 64);
    int ahi0 = __shfl(ua.i[0], hilane, 64), ahi1 = __shfl(ua.i[1], hilane, 64);
    int blo0 = __shfl(ub.i[0], lolane, 64), blo1 = __shfl(ub.i[1], lolane, 64);
    int bhi0 = __shfl(ub.i[0], hilane, 64), bhi1 = __shfl(ub.i[1], hilane, 64);
    union { short8 s; int i[4]; } up;
    const bool useA = (g < 2);
    up.i[0] = useA ? alo0 : blo0;
    up.i[1] = useA ? alo1 : blo1;
    up.i[2] = useA ? ahi0 : bhi0;
    up.i[3] = useA ? ahi1 : bhi1;
    const short8 pb8 = up.s;
    // ---- PV: frag-major streaming V loads from L2, K=32 ----
    const short* vp = vtt + (((long)p * 32 + dh * 16) * 64 + lane) * 8;
#pragma unroll
    for (int half = 0; half < 2; ++half) {
      short8 va[8];
#pragma unroll
      for (int j = 0; j < 8; ++j)
        va[j] = *(const short8*)(vp + (half * 8 + j) * 512);
      __builtin_amdgcn_s_setprio(1);
#pragma unroll
      for (int j = 0; j < 8; ++j)
        oacc[half * 8 + j] = __builtin_amdgcn_mfma_f32_16x16x32_bf16(va[j], pb8, oacc[half * 8 + j], 0, 0, 0);
      __builtin_amdgcn_s_setprio(0);
    }
    __syncthreads();
  }
#undef FL_STAGE

  // denominator for query q0+ln: sum over g-groups (within this wave)
  lsum += __shfl_xor(lsum, 16, 64);
  lsum += __shfl_xor(lsum, 32, 64);
  const float inv = 1.0f / fmaxf(lsum, 1e-30f);

  // O^T tile -> bf16 direct: row=g*4+r -> d = vbase+nt*16+g*4+r, col=ln -> q
  short* orow = obuf + ((long)h * S_LEN + q0 + ln) * 512 + vbase + g * 4;
#pragma unroll
  for (int nt = 0; nt < 16; ++nt) {
    unsigned lo = (unsigned)f2bf_bits(oacc[nt][0] * inv) | ((unsigned)f2bf_bits(oacc[nt][1] * inv) << 16);
    unsigned hi = (unsigned)f2bf_bits(oacc[nt][2] * inv) | ((unsigned)f2bf_bits(oacc[nt][3] * inv) << 16);
    unsigned long long st = (unsigned long long)lo | ((unsigned long long)hi << 32);
    *(unsigned long long*)(orow + nt * 16) = st;
  }
}

// ---------------------------------------------------------------------------
// Host launch
// ---------------------------------------------------------------------------
extern "C" void kernel_launch(void* const* d_in, const int* in_sizes, int n_in,
                              void* d_out, int out_size, void* d_ws, size_t ws_size,
                              hipStream_t stream) {
  (void)in_sizes; (void)n_in; (void)out_size; (void)ws_size;
  const float* x      = (const float*)d_in[0];
  const float* cosp   = (const float*)d_in[1];
  const float* sinp   = (const float*)d_in[2];
  const float* wq     = (const float*)d_in[3];
  const float* wkv_a  = (const float*)d_in[4];
  const float* normw  = (const float*)d_in[5];
  const float* wkv_b  = (const float*)d_in[6];
  const float* wo     = (const float*)d_in[7];
  float* out = (float*)d_out;

  float* ws = (float*)d_ws;
  float* qbufR  = ws;                                  // region A: [S,3072] f32-sized (25.2 MB)
  float* kvold  = qbufR + (long)S_LEN * 3072;          // wkv_a-pad bf16 region (4.7 MB)
  float* qhatR  = kvold + (long)S_LEN * D_QK;          // region B: 75.5 MB
  float* obufR  = qhatR + (long)H_N * S_LEN * D_QK;    // region C: 67 MB
  float* oprojR = obufR + (long)H_N * S_LEN * LORA;    // region D: 16.8 MB

  // region D: padded kv [S, KVF] f32 -> bf16 in place
  float* kvpad = oprojR;
  short* kbf = (short*)kvpad;                          // bf16 rows stride KVS
  short* wkvap = (short*)kvold;                        // padded wkv_a bf16 [KVF,2048]

  // region A aliases: qbufb (bf16 q proj, steps 2-6), then K/V transform
  // buffers (step 7+, qbufb dead) packed after it — no overlap in space.
  short* qbufb = (short*)qbufR;                        // [S,3072] bf16 (12.6 MB)
  short* kvt = qbufb + (long)S_LEN * 3072;             // [512][S] bf16, 2 MB
  short* ktt = kvt + (long)512 * S_LEN;                // 2.36 MB frag-major K
  short* vtt = ktt + (long)128 * 18 * 64 * 8;          // 2 MB frag-major V^T

  // region B aliases: qhatb bf16 (written steps 4/6, read step 8), then
  // post-flash bf16 scratch.
  short* qhatb  = (short*)qhatR;                       // [H][S][576] bf16 (37.7 MB)
  short* wkvbb  = qhatb + (long)H_N * S_LEN * D_QK;    // 4096x512
  short* oprojb = wkvbb + (long)4096 * 512;            // [S,2048] bf16
  short* wob    = oprojb + (long)2048 * 2048;          // 2048x2048

  // region C aliases: pre-flash bf16 scratch (dead by step 8), then flash
  // output obufb overlapping them in space only.
  short* xb   = (short*)obufR;                         // 2048x2048 (dead after step 3)
  short* wqb  = xb  + (long)2048 * 2048;               // 3072x2048 (dead after step 2)
  short* wukT = wqb + (long)3072 * 2048;               // 16x512x128 (dead after step 6)
  short* obufb = (short*)obufR;                        // [H][S][512] bf16 (33.5 MB, step 8+)

  // 1) casts for projections
  cast_f32_bf16<<<dim3(2048), 256, 0, stream>>>(x, xb, 2048 * 2048 / 8);
  cast_f32_bf16<<<dim3(3072), 256, 0, stream>>>(wq, wqb, 3072 * 2048 / 8);
  cast_f32_bf16<<<dim3(576), 256, 0, stream>>>(wkv_a, wkvap, 576 * 2048 / 8);
  zero_short8<<<dim3(64), 256, 0, stream>>>(wkvap + 576L * 2048, 64 * 2048 / 8);

  // 2) qbufb = bf16(x @ wq^T)  (bf16 MFMA, direct bf16 out)
  gemm_bf16_nt<<<dim3(3072 / 128, 2048 / 128, 1), 256, 0, stream>>>(
      xb, wqb, qbufb, 2048, 2048, 2048, 3072, 0, 0, 0, 1);

  // 3) kvpad = x @ wkv_a_pad^T  (f32 out; prep needs f32 for RMSNorm)
  gemm_bf16_nt<<<dim3(KVF / 128, 2048 / 128, 1), 256, 0, stream>>>(
      xb, wkvap, kvpad, 2048, 2048, 2048, KVF, 0, 0, 0, 0);

  // 4) RMSNorm + RoPE (kvpad -> kbf bf16 in place; q_pe -> qhatb tail bf16)
  prep_kernel<<<dim3(S_LEN), 64, 0, stream>>>(kvpad, qbufb, qhatb, cosp, sinp, normw);

  // 5) build wukT
  transpose_wuk<<<dim3(4, 16, 16), 256, 0, stream>>>(wkv_b, wukT);

  // 6) qhatb[:, :512] = bf16(q_nope @ w_uk)  (batched bf16 MFMA NT vs wukT)
  gemm_bf16_nt<<<dim3(512 / 128, 2048 / 128, 16), 256, 0, stream>>>(
      qbufb, wukT, qhatb, 128, 3072, 128, 576,
      192L, 512L * 128, (long)S_LEN * D_QK, 1);

  // 7) K/V layout transforms
  transpose_v<<<dim3(16, 64), 256, 0, stream>>>(kbf, kvt);
  build_ktt<<<dim3(128), 256, 0, stream>>>(kbf, ktt);
  build_vtt<<<dim3(64), 256, 0, stream>>>(kvt, vtt);

  // 8) flash attention -> obufb bf16  (32-key double-buffered staging)
  flash_reg<<<dim3(1024), 256, 0, stream>>>(qhatb, ktt, vtt, obufb);

  // 9) cast w_uv source
  cast_f32_bf16<<<dim3(1024), 256, 0, stream>>>(wkv_b, wkvbb, 4096 * 512 / 8);

  // 10) oprojb[s, h*128+d] = bf16(sum_c obufb[h,s,c] * w_uv[h,d,c])
  gemm_bf16_nt<<<dim3(1, 2048 / 128, 16), 256, 0, stream>>>(
      obufb, wkvbb + 128L * 512, oprojb, 512, 512, 512, 2048,
      (long)S_LEN * 512, 256L * 512, 128L, 1);

  // 11) out = oprojb @ wo^T  (f32 out)
  cast_f32_bf16<<<dim3(2048), 256, 0, stream>>>(wo, wob, 2048 * 2048 / 8);
  gemm_bf16_nt<<<dim3(2048 / 128, 2048 / 128, 1), 256, 0, stream>>>(
      oprojb, wob, out, 2048, 2048, 2048, 2048, 0, 0, 0, 0);
}

// Round 7
// 452.284 us; speedup vs baseline: 1.2867x; 1.0219x over previous
//
#include <hip/hip_runtime.h>
#include <hip/hip_bf16.h>
#include <math.h>

// Problem constants
#define S_LEN 2048
#define DIM   2048
#define H_N   16
#define NOPE  128
#define ROPE  64
#define VD    128
#define LORA  512
#define D_QK  576
#define SCALE_F 0.07216878364870323f   // 192^-0.5
#define EPS_F 1e-6f
#define KVF 640                        // padded kv row (f32 elems)
#define KVS 1280                       // padded kv row (shorts)

typedef short short8 __attribute__((ext_vector_type(8)));
typedef short short4v __attribute__((ext_vector_type(4)));
typedef float floatx4 __attribute__((ext_vector_type(4)));

static __device__ inline unsigned short f2bf_bits(float f) {
  union { __hip_bfloat16 h; unsigned short u; } cv;
  cv.h = __float2bfloat16(f);
  return cv.u;
}

static __device__ inline float bf2f(unsigned short b) {
  union { unsigned u; float f; } cv;
  cv.u = (unsigned)b << 16;
  return cv.f;
}

// global_load_lds: LDS destination must be WAVE-UNIFORM; lane's 16B lands at
// base + lane*16 automatically.
static __device__ inline void gload_lds16(const short* gptr, short* lds_base_uniform) {
  __builtin_amdgcn_global_load_lds(
      (const __attribute__((address_space(1))) void*)gptr,
      (__attribute__((address_space(3))) void*)lds_base_uniform, 16, 0, 0);
}

// ---------------------------------------------------------------------------
// elementwise f32 -> bf16 cast, 8 elts/thread
// ---------------------------------------------------------------------------
__global__ __launch_bounds__(256) void cast_f32_bf16(
    const float* __restrict__ src, short* __restrict__ dst, int n8) {
  int i = blockIdx.x * 256 + threadIdx.x;
  if (i < n8) {
    float4 a = ((const float4*)src)[2 * i];
    float4 b = ((const float4*)src)[2 * i + 1];
    uint4 o;
    o.x = (unsigned)f2bf_bits(a.x) | ((unsigned)f2bf_bits(a.y) << 16);
    o.y = (unsigned)f2bf_bits(a.z) | ((unsigned)f2bf_bits(a.w) << 16);
    o.z = (unsigned)f2bf_bits(b.x) | ((unsigned)f2bf_bits(b.y) << 16);
    o.w = (unsigned)f2bf_bits(b.z) | ((unsigned)f2bf_bits(b.w) << 16);
    ((uint4*)dst)[i] = o;
  }
}

// zero n8 uint4-chunks (8 shorts each)
__global__ __launch_bounds__(256) void zero_short8(short* __restrict__ dst, int n8) {
  int i = blockIdx.x * 256 + threadIdx.x;
  if (i < n8) ((uint4*)dst)[i] = (uint4){0u, 0u, 0u, 0u};
}

// ---------------------------------------------------------------------------
// wukT[h][c][d] = wkv_b[h*256 + d][c]  (f32 in, bf16 out), c<512, d<128
// ---------------------------------------------------------------------------
__global__ __launch_bounds__(256) void transpose_wuk(
    const float* __restrict__ wkvb, short* __restrict__ wukT) {
  __shared__ float tile[32][33];
  const int h = blockIdx.z, c0 = blockIdx.y * 32, d0 = blockIdx.x * 32;
  const int t = threadIdx.x;
  const int r = t >> 3, c4 = (t & 7) * 4;
  float4 v = *(const float4*)(wkvb + ((long)h * 256 + d0 + r) * 512 + c0 + c4);
  tile[r][c4 + 0] = v.x; tile[r][c4 + 1] = v.y;
  tile[r][c4 + 2] = v.z; tile[r][c4 + 3] = v.w;
  __syncthreads();
  uint2 o;
  o.x = (unsigned)f2bf_bits(tile[c4 + 0][r]) | ((unsigned)f2bf_bits(tile[c4 + 1][r]) << 16);
  o.y = (unsigned)f2bf_bits(tile[c4 + 2][r]) | ((unsigned)f2bf_bits(tile[c4 + 3][r]) << 16);
  *(uint2*)(wukT + ((long)h * 512 + c0 + r) * 128 + d0 + c4) = o;
}

// ---------------------------------------------------------------------------
// bf16 MFMA NT GEMM: C[m,n] = sum_k A[m,k]*B[n,k]. Output f32 or bf16.
// Double-buffered LDS (2x16KB) with 1-deep prefetch.
// ---------------------------------------------------------------------------
__global__ __launch_bounds__(256) void gemm_bf16_nt(
    const short* __restrict__ A, const short* __restrict__ B, void* __restrict__ Cv,
    int K, int lda, int ldb, int ldc, long aB, long bB, long cB, int bf16out) {
  A += (long)blockIdx.z * aB;
  B += (long)blockIdx.z * bB;
  const int m0 = blockIdx.y * 128, n0 = blockIdx.x * 128;
  __shared__ short As[2][128 * 32];
  __shared__ short Bs[2][128 * 32];
  const int tid = threadIdx.x, w = tid >> 6, lane = tid & 63;
  const int ln = lane & 15, g = lane >> 4;
  const int mw = (w & 1) * 64, nw = (w >> 1) * 64;
  floatx4 acc[4][4];
#pragma unroll
  for (int i = 0; i < 4; ++i)
#pragma unroll
    for (int j = 0; j < 4; ++j) acc[i][j] = (floatx4){0.f, 0.f, 0.f, 0.f};

#define GEMM_STAGE(k0_, b_)                                                    \
  {                                                                            \
    _Pragma("unroll")                                                          \
    for (int i = 0; i < 2; ++i) {                                              \
      const int bc = (i * 4 + w) * 64;                                         \
      const int c = bc + lane;                                                 \
      const int row = c >> 2, quar = c & 3;                                    \
      gload_lds16(A + (long)(m0 + row) * lda + (k0_) + quar * 8, As[b_] + bc * 8); \
      gload_lds16(B + (long)(n0 + row) * ldb + (k0_) + quar * 8, Bs[b_] + bc * 8); \
    }                                                                          \
  }

  GEMM_STAGE(0, 0);
  __syncthreads();
  const int nk = K >> 5;
  for (int kt = 0; kt < nk; ++kt) {
    const int cb = kt & 1;
    if (kt + 1 < nk) GEMM_STAGE((kt + 1) << 5, cb ^ 1);
    short8 af[4], bf_[4];
#pragma unroll
    for (int mi = 0; mi < 4; ++mi)
      af[mi] = *(const short8*)(As[cb] + (mw + mi * 16 + ln) * 32 + g * 8);
#pragma unroll
    for (int ni = 0; ni < 4; ++ni)
      bf_[ni] = *(const short8*)(Bs[cb] + (nw + ni * 16 + ln) * 32 + g * 8);
#pragma unroll
    for (int mi = 0; mi < 4; ++mi)
#pragma unroll
      for (int ni = 0; ni < 4; ++ni)
        acc[mi][ni] = __builtin_amdgcn_mfma_f32_16x16x32_bf16(af[mi], bf_[ni], acc[mi][ni], 0, 0, 0);
    __syncthreads();
  }
#undef GEMM_STAGE
  if (bf16out) {
    short* Cs = (short*)Cv + (long)blockIdx.z * cB;
#pragma unroll
    for (int mi = 0; mi < 4; ++mi)
#pragma unroll
      for (int ni = 0; ni < 4; ++ni)
#pragma unroll
        for (int r = 0; r < 4; ++r)
          Cs[(long)(m0 + mw + mi * 16 + g * 4 + r) * ldc + n0 + nw + ni * 16 + ln] =
              (short)f2bf_bits(acc[mi][ni][r]);
  } else {
    float* C = (float*)Cv + (long)blockIdx.z * cB;
#pragma unroll
    for (int mi = 0; mi < 4; ++mi)
#pragma unroll
      for (int ni = 0; ni < 4; ++ni)
#pragma unroll
        for (int r = 0; r < 4; ++r)
          C[(long)(m0 + mw + mi * 16 + g * 4 + r) * ldc + n0 + nw + ni * 16 + ln] = acc[mi][ni][r];
  }
}

// ---------------------------------------------------------------------------
// prep: RMSNorm + RoPE on kv rows (f32 stride KVF) -> bf16 in place (short
// stride KVS, first 576 valid); q_pe RoPE from bf16 qbufb -> bf16 qhat tail
// ---------------------------------------------------------------------------
__global__ __launch_bounds__(64) void prep_kernel(
    float* kv, const short* __restrict__ qbufb, short* __restrict__ qhatb,
    const float* __restrict__ cosp, const float* __restrict__ sinp,
    const float* __restrict__ normw) {
  const int s = blockIdx.x;
  const int l = threadIdx.x;
  float* row = kv + (long)s * KVF;
  short* krow = (short*)kv + (long)s * KVS;

  float4 v0 = *(const float4*)(row + l * 8);
  float4 v1 = *(const float4*)(row + l * 8 + 4);
  float rx0 = 0.f, rx1 = 0.f, rc = 0.f, rs = 0.f;
  if (l < 32) {
    rc = cosp[s * 32 + l];
    rs = sinp[s * 32 + l];
    rx0 = row[512 + 2 * l];
    rx1 = row[512 + 2 * l + 1];
  }
  float4 w0 = *(const float4*)(normw + l * 8);
  float4 w1 = *(const float4*)(normw + l * 8 + 4);

  float ss = v0.x * v0.x + v0.y * v0.y + v0.z * v0.z + v0.w * v0.w +
             v1.x * v1.x + v1.y * v1.y + v1.z * v1.z + v1.w * v1.w;
#pragma unroll
  for (int off = 32; off; off >>= 1) ss += __shfl_xor(ss, off, 64);
  const float scale = rsqrtf(ss * (1.0f / (float)LORA) + EPS_F);
  v0.x *= scale * w0.x; v0.y *= scale * w0.y; v0.z *= scale * w0.z; v0.w *= scale * w0.w;
  v1.x *= scale * w1.x; v1.y *= scale * w1.y; v1.z *= scale * w1.z; v1.w *= scale * w1.w;

  uint4 pk;
  pk.x = (unsigned)f2bf_bits(v0.x) | ((unsigned)f2bf_bits(v0.y) << 16);
  pk.y = (unsigned)f2bf_bits(v0.z) | ((unsigned)f2bf_bits(v0.w) << 16);
  pk.z = (unsigned)f2bf_bits(v1.x) | ((unsigned)f2bf_bits(v1.y) << 16);
  pk.w = (unsigned)f2bf_bits(v1.z) | ((unsigned)f2bf_bits(v1.w) << 16);
  *(uint4*)(krow + l * 8) = pk;

  if (l < 32) {
    const float y0 = rx0 * rc - rx1 * rs;
    const float y1 = rx0 * rs + rx1 * rc;
    unsigned pr = (unsigned)f2bf_bits(y0) | ((unsigned)f2bf_bits(y1) << 16);
    *(unsigned*)(krow + 512 + 2 * l) = pr;
  }

#pragma unroll
  for (int it = 0; it < 8; ++it) {
    const int p = it * 64 + l;
    const int h = p >> 5;
    const int i = p & 31;
    const float c = cosp[s * 32 + i];
    const float sn = sinp[s * 32 + i];
    const short* qp = qbufb + (long)s * 3072 + h * 192 + NOPE;
    const unsigned uq = *(const unsigned*)(qp + 2 * i);
    const float x0 = bf2f((unsigned short)uq);
    const float x1 = bf2f((unsigned short)(uq >> 16));
    const float y0 = x0 * c - x1 * sn;
    const float y1 = x0 * sn + x1 * c;
    short* dst = qhatb + ((long)h * S_LEN + s) * D_QK + 512;
    *(unsigned*)(dst + 2 * i) = (unsigned)f2bf_bits(y0) | ((unsigned)f2bf_bits(y1) << 16);
  }
}

// ---------------------------------------------------------------------------
// Transpose V: kvt[d][s] = kbf[s][d], d<512. kbf rows stride KVS shorts.
// ---------------------------------------------------------------------------
__global__ __launch_bounds__(256) void transpose_v(
    const short* __restrict__ kbf, short* __restrict__ kvt) {
  __shared__ short tile[32][36];
  const int d0 = blockIdx.x * 32;
  const int s0 = blockIdx.y * 32;
  const int t = threadIdx.x;
  const int r = t >> 3;
  const int c4 = (t & 7) * 4;
  uint2 v = *(const uint2*)(kbf + (long)(s0 + r) * KVS + d0 + c4);
  *(uint2*)(&tile[r][c4]) = v;
  __syncthreads();
  uint2 o;
  o.x = (unsigned)(unsigned short)tile[c4 + 0][r] | ((unsigned)(unsigned short)tile[c4 + 1][r] << 16);
  o.y = (unsigned)(unsigned short)tile[c4 + 2][r] | ((unsigned)(unsigned short)tile[c4 + 3][r] << 16);
  *(uint2*)(kvt + (long)(d0 + r) * S_LEN + s0 + c4) = o;
}

// ---------------------------------------------------------------------------
// Fragment-major K: ktt[kt][c][lane][8]
// ---------------------------------------------------------------------------
__global__ __launch_bounds__(256) void build_ktt(
    const short* __restrict__ kbf, short* __restrict__ ktt) {
  const int kt = blockIdx.x;                     // 0..127
  for (int idx = threadIdx.x; idx < 18 * 64; idx += 256) {
    const int c = idx >> 6, l = idx & 63;
    const int ln = l & 15, g = l >> 4;
    uint4 v = *(const uint4*)(kbf + (long)(kt * 16 + ln) * KVS + c * 32 + g * 8);
    *(uint4*)(ktt + ((long)(kt * 18 + c) * 64 + l) * 8) = v;
  }
}

// ---------------------------------------------------------------------------
// Fragment-major V^T: vtt[kt][nt][lane][8]
// ---------------------------------------------------------------------------
__global__ __launch_bounds__(256) void build_vtt(
    const short* __restrict__ kvt, short* __restrict__ vtt) {
  const int kt = blockIdx.x;                     // 0..63
  for (int idx = threadIdx.x; idx < 32 * 64; idx += 256) {
    const int nt = idx >> 6, l = idx & 63;
    const int ln = l & 15, g = l >> 4;
    uint4 v = *(const uint4*)(kvt + (long)(nt * 16 + ln) * S_LEN + kt * 32 + g * 8);
    *(uint4*)(vtt + ((long)(kt * 32 + nt) * 64 + l) * 8) = v;
  }
}

// ---------------------------------------------------------------------------
// Flash v12: block = 256 thr = 4 waves = (2 heads x 2 dh) of one q-tile.
// DIAGNOSIS (r6): per pair-slot ~3390 cyc measured == 4 waves x 36
// ds_read_b128 x ~12cyc x 2 blocks -> LDS-read-pipe bound, AND half the QK
// work was computed twice (dh waves duplicate QK/softmax of the same head).
// CHANGES vs v11:
//  * QK split across the dh-wave pair: wave (h,dh) computes only its 16-key
//    half (18 MFMAs, 18 K-frag LDS reads), softmax on 4 scores, writes one
//    packed P short4 (ds_write_b64) into Pl[parity][head][q][key].
//  * PV is software-pipelined one pair behind: it reads the FULL 32-key
//    P-frag (one ds_read_b128) of pair p-1, whose writes were fenced by the
//    previous end-of-pair barrier -> still exactly ONE barrier per pair and
//    full-pair stage->drain distance.
//  * Shuffle net (8 bpermute + selects) deleted. Per block per pair:
//    MFMA 208->136, LDS b128 reads 144->76, exp 32->16.
//  * End: tiny cross-dh lsum exchange via LDS.
// ---------------------------------------------------------------------------
__global__ __launch_bounds__(256, 2) void flash_reg(
    const short* __restrict__ qhat,   // [H][S][576] bf16
    const short* __restrict__ ktt,    // [128][18][64][8] bf16 frag-major K
    const short* __restrict__ vtt,    // [64][32][64][8] bf16 frag-major V^T
    short* __restrict__ obuf) {       // [H][S][512] bf16
  const int bid = blockIdx.x;         // 0..1023
  const int hp = bid & 7;             // head pair
  const int v = bid >> 3;             // 0..127
  const int vi = v & 31, vj = v >> 5;
  const int qw = (vj == 0) ? 127 - vi : (vj == 1) ? 64 + vi : (vj == 2) ? 63 - vi : vi;
  const int q0 = qw * 16;
  const int tid = threadIdx.x;
  const int w = tid >> 6;             // wave 0..3
  const int lane = tid & 63;
  const int ln = lane & 15, g = lane >> 4;
  const int hh = w & 1;               // head parity within block
  const int h = hp * 2 + hh;
  const int dh = w >> 1;              // key-half for QK; d-half for PV
  const int vbase = dh * 256;
  const int qlim = q0 + ln;

  __shared__ short Kt[2][36 * 64 * 8];          // 72 KB double-buffered K pairs
  __shared__ __align__(16) short Pl[2][2][16][40]; // P^T [parity][head][q][key pad 40]
  __shared__ float Ls[4][16];                   // cross-dh lsum exchange

  // Q B-frags for this wave's head: n = ln (query), k = g*8+j  (bf16 direct)
  short8 qfr[18];
  {
    const short* qrow = qhat + ((long)h * S_LEN + q0 + ln) * D_QK;
#pragma unroll
    for (int c = 0; c < 18; ++c)
      qfr[c] = *(const short8*)(qrow + c * 32 + g * 8);
  }

  floatx4 oacc[16];
#pragma unroll
  for (int nt = 0; nt < 16; ++nt) oacc[nt] = (floatx4){0.f, 0.f, 0.f, 0.f};
  float lsum = 0.f;

  const int npairs = (qw + 2) >> 1;   // 32-key steps

#define FL_STAGE(pair_, b_)                                                    \
  {                                                                            \
    const short* ksrc_ = ktt + (long)(pair_) * (36 * 512);                     \
    _Pragma("unroll")                                                          \
    for (int i = 0; i < 9; ++i) {                                              \
      const int grp = i * 4 + w;                                               \
      gload_lds16(ksrc_ + (long)(grp * 64 + lane) * 8, Kt[b_] + grp * 512);    \
    }                                                                          \
  }

#define FL_PV(pp_, par_)                                                       \
  {                                                                            \
    const short8 pb8 = *(const short8*)(&Pl[par_][hh][ln][g * 8]);             \
    const short* vp = vtt + (((long)(pp_) * 32 + dh * 16) * 64 + lane) * 8;    \
    _Pragma("unroll")                                                          \
    for (int half = 0; half < 2; ++half) {                                     \
      short8 va[8];                                                            \
      _Pragma("unroll")                                                        \
      for (int j = 0; j < 8; ++j)                                              \
        va[j] = *(const short8*)(vp + (half * 8 + j) * 512);                   \
      __builtin_amdgcn_s_setprio(1);                                           \
      _Pragma("unroll")                                                        \
      for (int j = 0; j < 8; ++j)                                              \
        oacc[half * 8 + j] = __builtin_amdgcn_mfma_f32_16x16x32_bf16(          \
            va[j], pb8, oacc[half * 8 + j], 0, 0, 0);                          \
      __builtin_amdgcn_s_setprio(0);                                           \
    }                                                                          \
  }

  FL_STAGE(0, 0);
  __syncthreads();

  for (int p = 0; p < npairs; ++p) {
    const int cb = p & 1;
    if (p + 1 < npairs) FL_STAGE(p + 1, cb ^ 1);
    const int t0 = p * 32;
    // ---- QK^T on THIS WAVE'S 16-key half-tile (dh selects tile) ----
    const short* kb = Kt[cb] + dh * (18 * 512);
    floatx4 s0 = (floatx4){0.f, 0.f, 0.f, 0.f};
    floatx4 s1 = (floatx4){0.f, 0.f, 0.f, 0.f};
    __builtin_amdgcn_s_setprio(1);
#pragma unroll
    for (int c = 0; c < 18; c += 2) {
      short8 k0 = *(const short8*)(kb + (c * 64 + lane) * 8);
      short8 k1 = *(const short8*)(kb + ((c + 1) * 64 + lane) * 8);
      s0 = __builtin_amdgcn_mfma_f32_16x16x32_bf16(k0, qfr[c], s0, 0, 0, 0);
      s1 = __builtin_amdgcn_mfma_f32_16x16x32_bf16(k1, qfr[c + 1], s1, 0, 0, 0);
    }
    __builtin_amdgcn_s_setprio(0);
    // ---- softmax on 4 scores: keys t0 + dh*16 + 4g + r ----
    short4v p4;
    float psum = 0.f;
#pragma unroll
    for (int r = 0; r < 4; ++r) {
      const int ki = t0 + dh * 16 + g * 4 + r;
      float sc = fminf(fmaxf((s0[r] + s1[r]) * SCALE_F, -30.f), 30.f);
      float pv_ = (ki <= qlim) ? __expf(sc) : 0.f;
      psum += pv_;
      p4[r] = (short)f2bf_bits(pv_);
    }
    lsum += psum;
    // ---- publish P half-tile: [q=ln][key = dh*16 + 4g .. +3] ----
    union { short4v s; unsigned long long u; } upk;
    upk.s = p4;
    *(unsigned long long*)(&Pl[cb][hh][ln][dh * 16 + g * 4]) = upk.u;
    // ---- PV for pair p-1 (P fenced by previous barrier) ----
    if (p > 0) FL_PV(p - 1, cb ^ 1);
    __syncthreads();
  }
  // final pending PV
  FL_PV(npairs - 1, (npairs - 1) & 1);
#undef FL_PV
#undef FL_STAGE

  // denominator: reduce over g within wave, then exchange across dh waves
  lsum += __shfl_xor(lsum, 16, 64);
  lsum += __shfl_xor(lsum, 32, 64);
  if (g == 0) Ls[w][ln] = lsum;
  __syncthreads();
  lsum += Ls[w ^ 2][ln];
  const float inv = 1.0f / fmaxf(lsum, 1e-30f);

  // O^T tile -> bf16 direct: row=g*4+r -> d = vbase+nt*16+g*4+r, col=ln -> q
  short* orow = obuf + ((long)h * S_LEN + q0 + ln) * 512 + vbase + g * 4;
#pragma unroll
  for (int nt = 0; nt < 16; ++nt) {
    unsigned lo = (unsigned)f2bf_bits(oacc[nt][0] * inv) | ((unsigned)f2bf_bits(oacc[nt][1] * inv) << 16);
    unsigned hi = (unsigned)f2bf_bits(oacc[nt][2] * inv) | ((unsigned)f2bf_bits(oacc[nt][3] * inv) << 16);
    unsigned long long st = (unsigned long long)lo | ((unsigned long long)hi << 32);
    *(unsigned long long*)(orow + nt * 16) = st;
  }
}

// ---------------------------------------------------------------------------
// Host launch
// ---------------------------------------------------------------------------
extern "C" void kernel_launch(void* const* d_in, const int* in_sizes, int n_in,
                              void* d_out, int out_size, void* d_ws, size_t ws_size,
                              hipStream_t stream) {
  (void)in_sizes; (void)n_in; (void)out_size; (void)ws_size;
  const float* x      = (const float*)d_in[0];
  const float* cosp   = (const float*)d_in[1];
  const float* sinp   = (const float*)d_in[2];
  const float* wq     = (const float*)d_in[3];
  const float* wkv_a  = (const float*)d_in[4];
  const float* normw  = (const float*)d_in[5];
  const float* wkv_b  = (const float*)d_in[6];
  const float* wo     = (const float*)d_in[7];
  float* out = (float*)d_out;

  float* ws = (float*)d_ws;
  float* qbufR  = ws;                                  // region A: [S,3072] f32-sized (25.2 MB)
  float* kvold  = qbufR + (long)S_LEN * 3072;          // wkv_a-pad bf16 region (4.7 MB)
  float* qhatR  = kvold + (long)S_LEN * D_QK;          // region B: 75.5 MB
  float* obufR  = qhatR + (long)H_N * S_LEN * D_QK;    // region C: 67 MB
  float* oprojR = obufR + (long)H_N * S_LEN * LORA;    // region D: 16.8 MB

  // region D: padded kv [S, KVF] f32 -> bf16 in place
  float* kvpad = oprojR;
  short* kbf = (short*)kvpad;                          // bf16 rows stride KVS
  short* wkvap = (short*)kvold;                        // padded wkv_a bf16 [KVF,2048]

  // region A aliases: qbufb (bf16 q proj, steps 2-6), then K/V transform
  // buffers (step 7+, qbufb dead) packed after it — no overlap in space.
  short* qbufb = (short*)qbufR;                        // [S,3072] bf16 (12.6 MB)
  short* kvt = qbufb + (long)S_LEN * 3072;             // [512][S] bf16, 2 MB
  short* ktt = kvt + (long)512 * S_LEN;                // 2.36 MB frag-major K
  short* vtt = ktt + (long)128 * 18 * 64 * 8;          // 2 MB frag-major V^T

  // region B aliases: qhatb bf16 (written steps 4/6, read step 8), then
  // post-flash bf16 scratch.
  short* qhatb  = (short*)qhatR;                       // [H][S][576] bf16 (37.7 MB)
  short* wkvbb  = qhatb + (long)H_N * S_LEN * D_QK;    // 4096x512
  short* oprojb = wkvbb + (long)4096 * 512;            // [S,2048] bf16
  short* wob    = oprojb + (long)2048 * 2048;          // 2048x2048

  // region C aliases: pre-flash bf16 scratch (dead by step 8), then flash
  // output obufb overlapping them in space only.
  short* xb   = (short*)obufR;                         // 2048x2048 (dead after step 3)
  short* wqb  = xb  + (long)2048 * 2048;               // 3072x2048 (dead after step 2)
  short* wukT = wqb + (long)3072 * 2048;               // 16x512x128 (dead after step 6)
  short* obufb = (short*)obufR;                        // [H][S][512] bf16 (33.5 MB, step 8+)

  // 1) casts for projections
  cast_f32_bf16<<<dim3(2048), 256, 0, stream>>>(x, xb, 2048 * 2048 / 8);
  cast_f32_bf16<<<dim3(3072), 256, 0, stream>>>(wq, wqb, 3072 * 2048 / 8);
  cast_f32_bf16<<<dim3(576), 256, 0, stream>>>(wkv_a, wkvap, 576 * 2048 / 8);
  zero_short8<<<dim3(64), 256, 0, stream>>>(wkvap + 576L * 2048, 64 * 2048 / 8);

  // 2) qbufb = bf16(x @ wq^T)  (bf16 MFMA, direct bf16 out)
  gemm_bf16_nt<<<dim3(3072 / 128, 2048 / 128, 1), 256, 0, stream>>>(
      xb, wqb, qbufb, 2048, 2048, 2048, 3072, 0, 0, 0, 1);

  // 3) kvpad = x @ wkv_a_pad^T  (f32 out; prep needs f32 for RMSNorm)
  gemm_bf16_nt<<<dim3(KVF / 128, 2048 / 128, 1), 256, 0, stream>>>(
      xb, wkvap, kvpad, 2048, 2048, 2048, KVF, 0, 0, 0, 0);

  // 4) RMSNorm + RoPE (kvpad -> kbf bf16 in place; q_pe -> qhatb tail bf16)
  prep_kernel<<<dim3(S_LEN), 64, 0, stream>>>(kvpad, qbufb, qhatb, cosp, sinp, normw);

  // 5) build wukT
  transpose_wuk<<<dim3(4, 16, 16), 256, 0, stream>>>(wkv_b, wukT);

  // 6) qhatb[:, :512] = bf16(q_nope @ w_uk)  (batched bf16 MFMA NT vs wukT)
  gemm_bf16_nt<<<dim3(512 / 128, 2048 / 128, 16), 256, 0, stream>>>(
      qbufb, wukT, qhatb, 128, 3072, 128, 576,
      192L, 512L * 128, (long)S_LEN * D_QK, 1);

  // 7) K/V layout transforms
  transpose_v<<<dim3(16, 64), 256, 0, stream>>>(kbf, kvt);
  build_ktt<<<dim3(128), 256, 0, stream>>>(kbf, ktt);
  build_vtt<<<dim3(64), 256, 0, stream>>>(kvt, vtt);

  // 8) flash attention -> obufb bf16  (dh-split QK + pipelined P exchange)
  flash_reg<<<dim3(1024), 256, 0, stream>>>(qhatb, ktt, vtt, obufb);

  // 9) cast w_uv source
  cast_f32_bf16<<<dim3(1024), 256, 0, stream>>>(wkv_b, wkvbb, 4096 * 512 / 8);

  // 10) oprojb[s, h*128+d] = bf16(sum_c obufb[h,s,c] * w_uv[h,d,c])
  gemm_bf16_nt<<<dim3(1, 2048 / 128, 16), 256, 0, stream>>>(
      obufb, wkvbb + 128L * 512, oprojb, 512, 512, 512, 2048,
      (long)S_LEN * 512, 256L * 512, 128L, 1);

  // 11) out = oprojb @ wo^T  (f32 out)
  cast_f32_bf16<<<dim3(2048), 256, 0, stream>>>(wo, wob, 2048 * 2048 / 8);
  gemm_bf16_nt<<<dim3(2048 / 128, 2048 / 128, 1), 256, 0, stream>>>(
      oprojb, wob, out, 2048, 2048, 2048, 2048, 0, 0, 0, 0);
}